// Round 3
// baseline (231.329 us; speedup 1.0000x reference)
//
#include <hip/hip_runtime.h>

// RandomShifts: out[n,c,i,j] = x[n,c, clamp(i+dy,0,83), clamp(j+dx,0,83)],
// dx = sx-4, dy = sy-4.  x: (512,9,84,84) fp32, shift: (512,2) int32.
// HBM-bound both ways (poison fill evicts L3 before kernel): floor ~40 us.

#define CBn  9
#define HBn  84
#define WBn  84
#define IMG  (HBn * WBn)   // 7056 floats per (n,c) image

// 4-byte-aligned 16-byte access (dwordx4 needs only dword alignment on CDNA)
struct __attribute__((packed, aligned(4))) f4u { float a, b, c, d; };

__global__ __launch_bounds__(256) void random_shifts_kernel(
    const float* __restrict__ x,
    const int*   __restrict__ shift,
    float*       __restrict__ out)
{
    const int nc = blockIdx.x;               // one block per (n,c): 4608 blocks
    const int n  = nc / CBn;                 // wave-uniform -> scalar shift loads
    const int dx = shift[2 * n]     - 4;     // [-4, 4]
    const int dy = shift[2 * n + 1] - 4;     // [-4, 4]

    const int tid = threadIdx.x;
    if (tid >= 252) return;                  // 252 = 12 rows x 21 float4/row

    const int r0 = tid / 21;                 // 0..11  (computed once)
    const int j4 = tid - r0 * 21;            // 0..20
    const int cs = (j4 << 2) + dx;           // loop-invariant source col start

    const float* __restrict__ img = x   + (size_t)nc * IMG;
    float*       __restrict__ dst = out + (size_t)nc * IMG + (j4 << 2);

    const bool interior = (cs >= 0) & (cs <= WBn - 4);
    // loop-invariant clamped indices for the (at most one) edge column group
    const int c0 = min(max(cs,     0), WBn - 1);
    const int c1 = min(max(cs + 1, 0), WBn - 1);
    const int c2 = min(max(cs + 2, 0), WBn - 1);
    const int c3 = min(max(cs + 3, 0), WBn - 1);

#pragma unroll
    for (int k = 0; k < 7; ++k) {            // 7 x 12 rows = 84 rows
        const int i  = k * 12 + r0;
        int si = i + dy;
        si = min(max(si, 0), HBn - 1);
        const float* srow = img + si * WBn;
        float4 v;
        if (interior) {
            const f4u u = *reinterpret_cast<const f4u*>(srow + cs);
            v = make_float4(u.a, u.b, u.c, u.d);
        } else {
            v = make_float4(srow[c0], srow[c1], srow[c2], srow[c3]);
        }
        *reinterpret_cast<float4*>(dst + i * WBn) = v;   // 16B-aligned
    }
}

extern "C" void kernel_launch(void* const* d_in, const int* in_sizes, int n_in,
                              void* d_out, int out_size, void* d_ws, size_t ws_size,
                              hipStream_t stream) {
    const float* x     = (const float*)d_in[0];
    const int*   shift = (const int*)d_in[1];
    float*       out   = (float*)d_out;

    random_shifts_kernel<<<512 * CBn, 256, 0, stream>>>(x, shift, out);
}